// Round 17
// baseline (170.917 us; speedup 1.0000x reference)
//
#include <hip/hip_runtime.h>
#include <math.h>

typedef __attribute__((ext_vector_type(8))) short bf16x8;
typedef __attribute__((ext_vector_type(4))) float f32x4;
typedef unsigned short u16;
typedef unsigned int u32;

#define BQ 1024
#define NCAND 40000
#define ROWS_TOT 41024
#define NF 16
#define NFREQ 32
#define DEMB 48
#define KDIM 800          // 784 padded to 800 (K % 32 == 0)
#define ASTRIDE 808       // LDS row stride in bf16
#define DIM 512
#define NCLS 10
#define NCHUNK 8
#define CHUNKSZ 5000
#define CT2_PER_CHUNK 20  // ceil(5000/256)
#define NCT2 160          // 8 chunks * 20 tiles
#define PSTRIDE 136       // P-tile row stride in bf16 (128 j + pad)
#define MROWS 64          // rows per k_encode block
#define TWO_PI 6.28318530717958647692f

__device__ __forceinline__ u16 f2bf(float f) {
  u32 u = __float_as_uint(f);
  u32 r = u + 0x7fffu + ((u >> 16) & 1u);  // RNE
  return (u16)(r >> 16);
}
__device__ __forceinline__ float bf2f(u16 b) { return __uint_as_float(((u32)b) << 16); }
__device__ __forceinline__ u32 cvt_pk_bf16(float lo, float hi) {
  u32 r;
  asm("v_cvt_pk_bf16_f32 %0, %1, %2" : "=v"(r) : "v"(lo), "v"(hi));
  return r;
}

// ---- enc_w [784][512] f32 -> enc_wT [512][800] bf16, 64x64 LDS tile transpose ----
__global__ __launch_bounds__(256)
void k_prep(const float* __restrict__ enc_w, u16* __restrict__ enc_wT)
{
  __shared__ float tile[64][65];
  const int bk = blockIdx.x % 13;   // 13 * 64 = 832 covers K=800
  const int bn = blockIdx.x / 13;   // 8 * 64 = 512
#pragma unroll
  for (int e = 0; e < 16; ++e) {
    int r = e * 4 + (threadIdx.x >> 6);   // k-local
    int c = threadIdx.x & 63;             // n-local (coalesced)
    int k = bk * 64 + r;
    tile[r][c] = (k < 784) ? enc_w[k * DIM + bn * 64 + c] : 0.f;
  }
  __syncthreads();
#pragma unroll
  for (int e = 0; e < 16; ++e) {
    int r = e * 4 + (threadIdx.x >> 6);   // n-local
    int c = threadIdx.x & 63;             // k-local (coalesced)
    int k = bk * 64 + c;
    if (k < KDIM)
      enc_wT[(size_t)(bn * 64 + r) * KDIM + k] = f2bf(tile[c][r]);
  }
}

// ---- PLR encode (MFMA) + [64x800]@[800x512] MFMA + norms ----
// 1024 threads / 16 waves; wave w: phase1 rows w*4..+3; phase2 cols w*32..+31.
__global__ __launch_bounds__(1024, 4)
void k_encode(const float* __restrict__ xq_num, const float* __restrict__ xq_cat,
              const float* __restrict__ xc_num, const float* __restrict__ xc_cat,
              const float* __restrict__ freq, const float* __restrict__ lin_w,
              const float* __restrict__ lin_b, const u16* __restrict__ enc_wT,
              const float* __restrict__ enc_b,
              u16* __restrict__ h_bf, float* __restrict__ norms)
{
  __shared__ u16 a_s[MROWS * ASTRIDE];     // 103.4 KB
  __shared__ float norm_s[MROWS];

  const int t = threadIdx.x;
  const int row0 = blockIdx.x * MROWS;
  const bool isq = (row0 < BQ);
  const float* __restrict__ xnum = isq ? xq_num : xc_num;
  const float* __restrict__ xcat = isq ? xq_cat : xc_cat;
  const int rbase = isq ? row0 : (row0 - BQ);

  const int wid = t >> 6, l = t & 63, hi = l >> 4, lo = l & 15;

  if (t < MROWS) norm_s[t] = 0.f;
  for (int i = t; i < MROWS * 16; i += 1024) {
    int r = i >> 4, c = i & 15;
    a_s[r * ASTRIDE + 768 + c] = f2bf(xcat[(rbase + r) * NF + c]);
  }
  for (int i = t; i < MROWS * 24; i += 1024) {
    int r = i / 24, c = i - r * 24;
    a_s[r * ASTRIDE + 784 + c] = 0;
  }

  // ---- phase 1: emb = relu(feats @ lin_w + b) via MFMA, feats never touch LDS.
  {
    float fq[8];
    *(float4*)&fq[0] = *(const float4*)&freq[lo * NFREQ + hi * 8];
    *(float4*)&fq[4] = *(const float4*)&freq[lo * NFREQ + hi * 8 + 4];
    float xv[4];
#pragma unroll
    for (int mi = 0; mi < 4; ++mi)
      xv[mi] = xnum[(rbase + wid * 4 + mi) * NF + lo];

    bf16x8 lwb[2][3];
#pragma unroll
    for (int kf = 0; kf < 2; ++kf)
#pragma unroll
      for (int nf = 0; nf < 3; ++nf)
#pragma unroll
        for (int e = 0; e < 8; ++e)
          lwb[kf][nf][e] = (short)f2bf(lin_w[(kf * 32 + hi * 8 + e) * DEMB + nf * 16 + lo]);
    float lb[3];
#pragma unroll
    for (int nf = 0; nf < 3; ++nf) lb[nf] = lin_b[nf * 16 + lo];

#pragma unroll
    for (int mi = 0; mi < 4; ++mi) {
      bf16x8 ac, as_;
#pragma unroll
      for (int e = 0; e < 8; ++e) {
        float tt = TWO_PI * fq[e] * xv[mi];
        ac[e] = (short)f2bf(__cosf(tt));
        as_[e] = (short)f2bf(__sinf(tt));
      }
#pragma unroll
      for (int nf = 0; nf < 3; ++nf) {
        f32x4 ec = {0.f, 0.f, 0.f, 0.f};
        ec = __builtin_amdgcn_mfma_f32_16x16x32_bf16(ac, lwb[0][nf], ec, 0, 0, 0);
        ec = __builtin_amdgcn_mfma_f32_16x16x32_bf16(as_, lwb[1][nf], ec, 0, 0, 0);
#pragma unroll
        for (int reg = 0; reg < 4; ++reg) {
          int f = hi * 4 + reg;
          int r = wid * 4 + mi;
          float v = fmaxf(ec[reg] + lb[nf], 0.f);
          a_s[r * ASTRIDE + f * DEMB + nf * 16 + lo] = f2bf(v);
        }
      }
    }
  }
  __syncthreads();

  // ---- phase 2: [64 x 800] @ [800 x 32-per-wave]; 2-deep ping-pong pipeline.
  f32x4 acc[4][2];
#pragma unroll
  for (int mf = 0; mf < 4; ++mf)
#pragma unroll
    for (int nf = 0; nf < 2; ++nf) acc[mf][nf] = 0.f;

  const u16* bwbase = enc_wT + (size_t)(wid * 32 + lo) * KDIM + hi * 8;
  const u16* asbase = a_s + lo * ASTRIDE + hi * 8;

  bf16x8 afb[2][4], bwb[2][2];

#define LOADK(kt, b)                                                          \
  {                                                                           \
    _Pragma("unroll")                                                         \
    for (int nf = 0; nf < 2; ++nf)                                            \
      bwb[b][nf] = *(const bf16x8*)(bwbase + (size_t)nf * 16 * KDIM + (kt) * 32); \
    _Pragma("unroll")                                                         \
    for (int mf = 0; mf < 4; ++mf)                                            \
      afb[b][mf] = *(const bf16x8*)(asbase + mf * 16 * ASTRIDE + (kt) * 32);  \
  }
#define MFMAK(b)                                                              \
  {                                                                           \
    _Pragma("unroll")                                                         \
    for (int mf = 0; mf < 4; ++mf)                                            \
      _Pragma("unroll")                                                       \
      for (int nf = 0; nf < 2; ++nf)                                          \
        acc[mf][nf] =                                                         \
            __builtin_amdgcn_mfma_f32_16x16x32_bf16(afb[b][mf], bwb[b][nf],   \
                                                    acc[mf][nf], 0, 0, 0);    \
  }

  LOADK(0, 0);
#pragma unroll
  for (int i = 0; i < 25; ++i) {
    if (i < 24) LOADK(i + 1, (i + 1) & 1);
    __builtin_amdgcn_s_setprio(1);
    MFMAK(i & 1);
    __builtin_amdgcn_s_setprio(0);
  }
#undef LOADK
#undef MFMAK

  float encb_v[2];
#pragma unroll
  for (int nf = 0; nf < 2; ++nf) encb_v[nf] = enc_b[wid * 32 + nf * 16 + lo];
  float nacc[4][4];
#pragma unroll
  for (int mf = 0; mf < 4; ++mf)
#pragma unroll
    for (int r = 0; r < 4; ++r) nacc[mf][r] = 0.f;

#pragma unroll
  for (int mf = 0; mf < 4; ++mf)
#pragma unroll
    for (int nf = 0; nf < 2; ++nf)
#pragma unroll
      for (int r = 0; r < 4; ++r) {
        int m = mf * 16 + hi * 4 + r;
        int n = wid * 32 + nf * 16 + lo;
        float hv = acc[mf][nf][r] + encb_v[nf];
        u16 ub = f2bf(hv);
        h_bf[(size_t)(row0 + m) * DIM + n] = ub;
        float hb = bf2f(ub);
        nacc[mf][r] = fmaf(hb, hb, nacc[mf][r]);
      }
#pragma unroll
  for (int mf = 0; mf < 4; ++mf)
#pragma unroll
    for (int r = 0; r < 4; ++r) {
      float v = nacc[mf][r];
      v += __shfl_xor(v, 1); v += __shfl_xor(v, 2);
      v += __shfl_xor(v, 4); v += __shfl_xor(v, 8);
      if (lo == 0) atomicAdd(&norm_s[mf * 16 + hi * 4 + r], v);
    }
  __syncthreads();
  if (t < MROWS) norms[row0 + t] = norm_s[t];
}

// ---- fused distance MFMA (256c x 256q, BK=32, 1024 threads / 16 waves) ----
// LDS ~74 KB -> 2 blocks/CU (8 waves/SIMD): TLP covers barrier/latency gaps.
// grid: 640 flat, XCD-swizzled: xcd=flat%8 owns chunk xcd (20 ct2 x 4 qt).
__global__ __launch_bounds__(1024, 4)
void k_dist(const u16* __restrict__ h_bf, const float* __restrict__ norms,
            const int* __restrict__ cand_y,
            float* __restrict__ cls_part, float* __restrict__ lse_part)
{
  // union: dbuf 2 x (A 256x32 + B 256x32) = 32768 u16 (64 KB)
  //      | epilogue P_s[256][136] = 34816 u16 (69.6 KB)
  __shared__ __align__(16) u16 AB_s[34816];
  __shared__ float qn_s[256];
  __shared__ float cn_s[256];
  __shared__ int cy_s[256];
  __shared__ float lse_s[256];

  u16* P_s = AB_s;

  const int flat = blockIdx.x;
  const int xcd = flat & 7;
  const int i = flat >> 3;                 // 0..79
  const int ctl = i >> 2;                  // 0..19
  const int qt = i & 3;                    // 0..3
  const int chunk = xcd;
  const int ct2 = chunk * CT2_PER_CHUNK + ctl;

  const int t = threadIdx.x;
  const int cand0 = chunk * CHUNKSZ + ctl * 256;
  const int cend = chunk * CHUNKSZ + CHUNKSZ;
  const int q0 = qt * 256;

  if (t < 256) {
    lse_s[t] = 0.f;
    qn_s[t] = norms[q0 + t];
    int j = cand0 + t; if (j > cend - 1) j = cend - 1;
    cn_s[t] = norms[BQ + j];
    cy_s[t] = cand_y[j];
  }

  const int wid = t >> 6, l = t & 63, hi = l >> 4, lo = l & 15;
  const int wc = wid & 3, wq = wid >> 2;   // wave: cand quarter (64) x q quarter (64)

  // stage one K-step (BK=32): A(256x32) -> AB_s[dstoff], B -> +8192 (u16 units).
  // 1024 threads -> exactly 1 seg/thread per operand (2 loads/thread).
  // LDS dest LINEAR; source col pre-swizzled (inverse of read swizzle).
#define STAGE(dstoff, kt)                                                      \
  {                                                                            \
    int lrow = t >> 2;                                                         \
    int scol = ((t & 3) * 16) ^ ((lrow & 3) << 4);                             \
    int crow = cand0 + lrow; if (crow > cend - 1) crow = cend - 1;             \
    const u16* srcA = h_bf + (size_t)(BQ + crow) * DIM + (kt) * 32 + (scol >> 1); \
    __builtin_amdgcn_global_load_lds(                                          \
        (const __attribute__((address_space(1))) u32*)srcA,                    \
        (__attribute__((address_space(3))) u32*)(AB_s + (dstoff) + t * 8),     \
        16, 0, 0);                                                             \
    const u16* srcB = h_bf + (size_t)(q0 + lrow) * DIM + (kt) * 32 + (scol >> 1); \
    __builtin_amdgcn_global_load_lds(                                          \
        (const __attribute__((address_space(1))) u32*)srcB,                    \
        (__attribute__((address_space(3))) u32*)(AB_s + (dstoff) + 8192 + t * 8), \
        16, 0, 0);                                                             \
  }

  f32x4 acc[4][4];
#pragma unroll
  for (int mi = 0; mi < 4; ++mi)
#pragma unroll
    for (int ni = 0; ni < 4; ++ni) acc[mi][ni] = 0.f;

  STAGE(0, 0);          // 2 loads/thread in flight
  STAGE(16384, 1);      // 4 in flight

#pragma unroll
  for (int kt = 0; kt < 16; ++kt) {
    // wait ONLY for stage(kt): stage(kt+1)'s 2 may stay outstanding
    if (kt == 15) asm volatile("s_waitcnt vmcnt(0)" ::: "memory");
    else          asm volatile("s_waitcnt vmcnt(2)" ::: "memory");
    __builtin_amdgcn_s_barrier();            // all waves' stage(kt) landed
    __builtin_amdgcn_sched_barrier(0);

    const u16* Ac = AB_s + (kt & 1) * 16384;
    const u16* Bc = Ac + 8192;
    __builtin_amdgcn_s_setprio(1);
    {
      bf16x8 af[4], bq[4];
#pragma unroll
      for (int mi = 0; mi < 4; ++mi) {
        int row = wc * 64 + mi * 16 + lo;
        int byt = (hi * 16) ^ ((row & 3) << 4);
        af[mi] = *(const bf16x8*)&Ac[row * 32 + (byt >> 1)];
      }
#pragma unroll
      for (int ni = 0; ni < 4; ++ni) {
        int row = wq * 64 + ni * 16 + lo;
        int byt = (hi * 16) ^ ((row & 3) << 4);
        bq[ni] = *(const bf16x8*)&Bc[row * 32 + (byt >> 1)];
      }
#pragma unroll
      for (int mi = 0; mi < 4; ++mi)
#pragma unroll
        for (int ni = 0; ni < 4; ++ni)
          acc[mi][ni] = __builtin_amdgcn_mfma_f32_16x16x32_bf16(af[mi], bq[ni], acc[mi][ni], 0, 0, 0);
    }
    __builtin_amdgcn_s_setprio(0);
    __builtin_amdgcn_sched_barrier(0);
    __builtin_amdgcn_s_barrier();            // all waves done READING buf[kt&1]
    if (kt < 14) STAGE((kt & 1) * 16384, kt + 2);  // refill freed buffer
  }
#undef STAGE

  // epilogue: d2 -> dist -> e (packed to bf16 in regs) + lse partial
  float qv[4];
#pragma unroll
  for (int ni = 0; ni < 4; ++ni) qv[ni] = qn_s[wq * 64 + ni * 16 + lo];

  u32 pk[4][4][2];
  float lacc[4] = {0.f, 0.f, 0.f, 0.f};
#pragma unroll
  for (int mi = 0; mi < 4; ++mi)
#pragma unroll
    for (int ni = 0; ni < 4; ++ni) {
      float ev[4];
#pragma unroll
      for (int r = 0; r < 4; ++r) {
        int crow = wc * 64 + mi * 16 + hi * 4 + r;
        bool valid = (cand0 + crow) < cend;
        float d2 = fmaf(-2.f, acc[mi][ni][r], cn_s[crow] + qv[ni]);
        float dist = __builtin_amdgcn_sqrtf(fmaxf(d2, 1e-12f));
        float e = valid ? __expf(-dist) : 0.f;
        ev[r] = e;
        lacc[ni] += valid ? __expf(e) : 0.f;
      }
      pk[mi][ni][0] = cvt_pk_bf16(ev[0], ev[1]);
      pk[mi][ni][1] = cvt_pk_bf16(ev[2], ev[3]);
    }

  // LSE partial: reduce across the 4 hi-groups (j spread over hi)
#pragma unroll
  for (int ni = 0; ni < 4; ++ni) {
    float v = lacc[ni];
    v += __shfl_xor(v, 16); v += __shfl_xor(v, 32);
    if (hi == 0) atomicAdd(&lse_s[wq * 64 + ni * 16 + lo], v);
  }

  // class-sum GEMM in two cand-halves of 128: P_s[256 q][128 j + pad].
  f32x4 accc = {0.f, 0.f, 0.f, 0.f};
#pragma unroll
  for (int h = 0; h < 2; ++h) {
    __syncthreads();   // previous AB_s/P_s readers done
    if ((wc >> 1) == h) {
#pragma unroll
      for (int mi = 0; mi < 4; ++mi)
#pragma unroll
        for (int ni = 0; ni < 4; ++ni) {
          int q = wq * 64 + ni * 16 + lo;
          int j0 = (wc & 1) * 64 + mi * 16 + hi * 4;
          *(uint2*)&P_s[q * PSTRIDE + j0] = make_uint2(pk[mi][ni][0], pk[mi][ni][1]);
        }
    }
    __syncthreads();
    // each wave owns q-group wid*16..+15: out[q][c] += P[q][j 0..127] @ onehot
    const u16* Prow = P_s + (wid * 16 + lo) * PSTRIDE;
#pragma unroll
    for (int ks = 0; ks < 4; ++ks) {
      bf16x8 af = *(const bf16x8*)(Prow + ks * 32 + hi * 8);
      bf16x8 yb;
#pragma unroll
      for (int e = 0; e < 8; ++e) {
        int j = h * 128 + ks * 32 + hi * 8 + e;
        yb[e] = (short)((cy_s[j] == lo) ? 0x3F80 : 0);
      }
      accc = __builtin_amdgcn_mfma_f32_16x16x32_bf16(af, yb, accc, 0, 0, 0);
    }
  }
  if (lo < NCLS) {
#pragma unroll
    for (int reg = 0; reg < 4; ++reg) {
      int qq = wid * 16 + hi * 4 + reg;
      cls_part[((size_t)ct2 * BQ + (q0 + qq)) * NCLS + lo] = accc[reg];
    }
  }

  if (t < 256) lse_part[(size_t)ct2 * BQ + q0 + t] = lse_s[t];
}

// ---- combine partials over 160 cand tiles ----
__global__ __launch_bounds__(256)
void k_final(const float* __restrict__ cls_part, const float* __restrict__ lse_part,
             float* __restrict__ out)
{
  __shared__ float cls_sum[NCLS];
  __shared__ float ch_sum[NCHUNK];
  const int t = threadIdx.x;   // 0..255; tiles at t<160
  const int b = blockIdx.x;
  if (t < NCLS) cls_sum[t] = 0.f;
  if (t < NCHUNK) ch_sum[t] = 0.f;
  __syncthreads();

  float cs[NCLS];
  float ls = 0.f;
  if (t < NCT2) {
#pragma unroll
    for (int c = 0; c < NCLS; ++c) cs[c] = cls_part[((size_t)t * BQ + b) * NCLS + c];
    ls = lse_part[(size_t)t * BQ + b];
    atomicAdd(&ch_sum[t / CT2_PER_CHUNK], ls);
  } else {
#pragma unroll
    for (int c = 0; c < NCLS; ++c) cs[c] = 0.f;
  }
#pragma unroll
  for (int c = 0; c < NCLS; ++c) {
    float w = cs[c];
    w += __shfl_xor(w, 1); w += __shfl_xor(w, 2); w += __shfl_xor(w, 4);
    w += __shfl_xor(w, 8); w += __shfl_xor(w, 16); w += __shfl_xor(w, 32);
    if ((t & 63) == 0) atomicAdd(&cls_sum[c], w);
  }
  __syncthreads();
  if (t < NCLS) {
    float lse = 0.f;
#pragma unroll
    for (int ch = 0; ch < NCHUNK; ++ch) lse += logf(ch_sum[ch]);
    out[b * NCLS + t] = logf(cls_sum[t]) - lse;
  }
}

extern "C" void kernel_launch(void* const* d_in, const int* in_sizes, int n_in,
                              void* d_out, int out_size, void* d_ws, size_t ws_size,
                              hipStream_t stream)
{
  const float* xq_num = (const float*)d_in[0];
  const float* xq_cat = (const float*)d_in[1];
  // d_in[2] = y (unused)
  const float* xc_num = (const float*)d_in[3];
  const float* xc_cat = (const float*)d_in[4];
  const int* cand_y = (const int*)d_in[5];
  const float* freq = (const float*)d_in[6];
  const float* lin_w = (const float*)d_in[7];
  const float* lin_b = (const float*)d_in[8];
  const float* enc_w = (const float*)d_in[9];
  const float* enc_b = (const float*)d_in[10];

  u16* h_bf = (u16*)d_ws;                                        // 41024*512 bf16
  float* norms = (float*)((char*)d_ws + (size_t)ROWS_TOT * DIM * 2);
  float* cls_part = norms + ROWS_TOT;                            // [160][1024][10]
  float* lse_part = cls_part + (size_t)NCT2 * BQ * NCLS;         // [160][1024]
  u16* enc_wT = (u16*)(lse_part + (size_t)NCT2 * BQ);            // [512][800]
  float* out = (float*)d_out;

  hipLaunchKernelGGL(k_prep, dim3(13 * 8), dim3(256), 0, stream, enc_w, enc_wT);
  hipLaunchKernelGGL(k_encode, dim3(ROWS_TOT / MROWS), dim3(1024), 0, stream,
                     xq_num, xq_cat, xc_num, xc_cat, freq, lin_w, lin_b,
                     enc_wT, enc_b, h_bf, norms);
  hipLaunchKernelGGL(k_dist, dim3(NCT2 * 4), dim3(1024), 0, stream,
                     h_bf, norms, cand_y, cls_part, lse_part);
  hipLaunchKernelGGL(k_final, dim3(BQ), dim3(256), 0, stream,
                     cls_part, lse_part, out);
}

// Round 18
// 167.289 us; speedup vs baseline: 1.0217x; 1.0217x over previous
//
#include <hip/hip_runtime.h>
#include <math.h>

typedef __attribute__((ext_vector_type(8))) short bf16x8;
typedef __attribute__((ext_vector_type(4))) float f32x4;
typedef unsigned short u16;
typedef unsigned int u32;

#define BQ 1024
#define NCAND 40000
#define ROWS_TOT 41024
#define NF 16
#define NFREQ 32
#define DEMB 48
#define KDIM 800          // 784 padded to 800 (K % 32 == 0)
#define ASTRIDE 808       // LDS row stride in bf16
#define DIM 512
#define NCLS 10
#define NCHUNK 8
#define CHUNKSZ 5000
#define CT2_PER_CHUNK 20  // ceil(5000/256)
#define NCT2 160          // 8 chunks * 20 tiles
#define PSTRIDE 136       // P-tile row stride in bf16 (128 j + pad)
#define MROWS 64          // rows per k_encode block
#define TWO_PI 6.28318530717958647692f

__device__ __forceinline__ u16 f2bf(float f) {
  u32 u = __float_as_uint(f);
  u32 r = u + 0x7fffu + ((u >> 16) & 1u);  // RNE
  return (u16)(r >> 16);
}
__device__ __forceinline__ float bf2f(u16 b) { return __uint_as_float(((u32)b) << 16); }
__device__ __forceinline__ u32 cvt_pk_bf16(float lo, float hi) {
  u32 r;
  asm("v_cvt_pk_bf16_f32 %0, %1, %2" : "=v"(r) : "v"(lo), "v"(hi));
  return r;
}

// ---- enc_w [784][512] f32 -> enc_wT [512][800] bf16, 64x64 LDS tile transpose ----
__global__ __launch_bounds__(256)
void k_prep(const float* __restrict__ enc_w, u16* __restrict__ enc_wT)
{
  __shared__ float tile[64][65];
  const int bk = blockIdx.x % 13;   // 13 * 64 = 832 covers K=800
  const int bn = blockIdx.x / 13;   // 8 * 64 = 512
#pragma unroll
  for (int e = 0; e < 16; ++e) {
    int r = e * 4 + (threadIdx.x >> 6);   // k-local
    int c = threadIdx.x & 63;             // n-local (coalesced)
    int k = bk * 64 + r;
    tile[r][c] = (k < 784) ? enc_w[k * DIM + bn * 64 + c] : 0.f;
  }
  __syncthreads();
#pragma unroll
  for (int e = 0; e < 16; ++e) {
    int r = e * 4 + (threadIdx.x >> 6);   // n-local
    int c = threadIdx.x & 63;             // k-local (coalesced)
    int k = bk * 64 + c;
    if (k < KDIM)
      enc_wT[(size_t)(bn * 64 + r) * KDIM + k] = f2bf(tile[c][r]);
  }
}

// ---- PLR encode (MFMA) + [64x800]@[800x512] MFMA + norms ----
// 1024 threads / 16 waves; wave w: phase1 rows w*4..+3; phase2 cols w*32..+31,
// all 64 rows. 103 KB LDS; 4 waves/SIMD.
__global__ __launch_bounds__(1024, 4)
void k_encode(const float* __restrict__ xq_num, const float* __restrict__ xq_cat,
              const float* __restrict__ xc_num, const float* __restrict__ xc_cat,
              const float* __restrict__ freq, const float* __restrict__ lin_w,
              const float* __restrict__ lin_b, const u16* __restrict__ enc_wT,
              const float* __restrict__ enc_b,
              u16* __restrict__ h_bf, float* __restrict__ norms)
{
  __shared__ u16 a_s[MROWS * ASTRIDE];     // 103.4 KB
  __shared__ float norm_s[MROWS];

  const int t = threadIdx.x;
  const int row0 = blockIdx.x * MROWS;
  const bool isq = (row0 < BQ);
  const float* __restrict__ xnum = isq ? xq_num : xc_num;
  const float* __restrict__ xcat = isq ? xq_cat : xc_cat;
  const int rbase = isq ? row0 : (row0 - BQ);

  const int wid = t >> 6, l = t & 63, hi = l >> 4, lo = l & 15;

  if (t < MROWS) norm_s[t] = 0.f;
  for (int i = t; i < MROWS * 16; i += 1024) {
    int r = i >> 4, c = i & 15;
    a_s[r * ASTRIDE + 768 + c] = f2bf(xcat[(rbase + r) * NF + c]);
  }
  for (int i = t; i < MROWS * 24; i += 1024) {
    int r = i / 24, c = i - r * 24;
    a_s[r * ASTRIDE + 784 + c] = 0;
  }

  // ---- phase 1: emb = relu(feats @ lin_w + b) via MFMA, feats never touch LDS.
  // wave handles rows wid*4 .. +3 (each mi = one data row, all 16 fields).
  {
    float fq[8];
    *(float4*)&fq[0] = *(const float4*)&freq[lo * NFREQ + hi * 8];
    *(float4*)&fq[4] = *(const float4*)&freq[lo * NFREQ + hi * 8 + 4];
    float xv[4];
#pragma unroll
    for (int mi = 0; mi < 4; ++mi)
      xv[mi] = xnum[(rbase + wid * 4 + mi) * NF + lo];

    bf16x8 lwb[2][3];
#pragma unroll
    for (int kf = 0; kf < 2; ++kf)
#pragma unroll
      for (int nf = 0; nf < 3; ++nf)
#pragma unroll
        for (int e = 0; e < 8; ++e)
          lwb[kf][nf][e] = (short)f2bf(lin_w[(kf * 32 + hi * 8 + e) * DEMB + nf * 16 + lo]);
    float lb[3];
#pragma unroll
    for (int nf = 0; nf < 3; ++nf) lb[nf] = lin_b[nf * 16 + lo];

#pragma unroll
    for (int mi = 0; mi < 4; ++mi) {
      bf16x8 ac, as_;
#pragma unroll
      for (int e = 0; e < 8; ++e) {
        float tt = TWO_PI * fq[e] * xv[mi];
        ac[e] = (short)f2bf(__cosf(tt));
        as_[e] = (short)f2bf(__sinf(tt));
      }
#pragma unroll
      for (int nf = 0; nf < 3; ++nf) {
        f32x4 ec = {0.f, 0.f, 0.f, 0.f};
        ec = __builtin_amdgcn_mfma_f32_16x16x32_bf16(ac, lwb[0][nf], ec, 0, 0, 0);
        ec = __builtin_amdgcn_mfma_f32_16x16x32_bf16(as_, lwb[1][nf], ec, 0, 0, 0);
#pragma unroll
        for (int reg = 0; reg < 4; ++reg) {
          int f = hi * 4 + reg;
          int r = wid * 4 + mi;
          float v = fmaxf(ec[reg] + lb[nf], 0.f);
          a_s[r * ASTRIDE + f * DEMB + nf * 16 + lo] = f2bf(v);
        }
      }
    }
  }
  __syncthreads();

  // ---- phase 2: [64 x 800] @ [800 x 32-per-wave]; 2-deep ping-pong pipeline.
  f32x4 acc[4][2];
#pragma unroll
  for (int mf = 0; mf < 4; ++mf)
#pragma unroll
    for (int nf = 0; nf < 2; ++nf) acc[mf][nf] = 0.f;

  const u16* bwbase = enc_wT + (size_t)(wid * 32 + lo) * KDIM + hi * 8;
  const u16* asbase = a_s + lo * ASTRIDE + hi * 8;

  bf16x8 afb[2][4], bwb[2][2];

#define LOADK(kt, b)                                                          \
  {                                                                           \
    _Pragma("unroll")                                                         \
    for (int nf = 0; nf < 2; ++nf)                                            \
      bwb[b][nf] = *(const bf16x8*)(bwbase + (size_t)nf * 16 * KDIM + (kt) * 32); \
    _Pragma("unroll")                                                         \
    for (int mf = 0; mf < 4; ++mf)                                            \
      afb[b][mf] = *(const bf16x8*)(asbase + mf * 16 * ASTRIDE + (kt) * 32);  \
  }
#define MFMAK(b)                                                              \
  {                                                                           \
    _Pragma("unroll")                                                         \
    for (int mf = 0; mf < 4; ++mf)                                            \
      _Pragma("unroll")                                                       \
      for (int nf = 0; nf < 2; ++nf)                                          \
        acc[mf][nf] =                                                         \
            __builtin_amdgcn_mfma_f32_16x16x32_bf16(afb[b][mf], bwb[b][nf],   \
                                                    acc[mf][nf], 0, 0, 0);    \
  }

  LOADK(0, 0);
#pragma unroll
  for (int i = 0; i < 25; ++i) {
    if (i < 24) LOADK(i + 1, (i + 1) & 1);
    __builtin_amdgcn_s_setprio(1);
    MFMAK(i & 1);
    __builtin_amdgcn_s_setprio(0);
  }
#undef LOADK
#undef MFMAK

  float encb_v[2];
#pragma unroll
  for (int nf = 0; nf < 2; ++nf) encb_v[nf] = enc_b[wid * 32 + nf * 16 + lo];
  float nacc[4][4];
#pragma unroll
  for (int mf = 0; mf < 4; ++mf)
#pragma unroll
    for (int r = 0; r < 4; ++r) nacc[mf][r] = 0.f;

#pragma unroll
  for (int mf = 0; mf < 4; ++mf)
#pragma unroll
    for (int nf = 0; nf < 2; ++nf)
#pragma unroll
      for (int r = 0; r < 4; ++r) {
        int m = mf * 16 + hi * 4 + r;
        int n = wid * 32 + nf * 16 + lo;
        float hv = acc[mf][nf][r] + encb_v[nf];
        u16 ub = f2bf(hv);
        h_bf[(size_t)(row0 + m) * DIM + n] = ub;
        float hb = bf2f(ub);
        nacc[mf][r] = fmaf(hb, hb, nacc[mf][r]);
      }
#pragma unroll
  for (int mf = 0; mf < 4; ++mf)
#pragma unroll
    for (int r = 0; r < 4; ++r) {
      float v = nacc[mf][r];
      v += __shfl_xor(v, 1); v += __shfl_xor(v, 2);
      v += __shfl_xor(v, 4); v += __shfl_xor(v, 8);
      if (lo == 0) atomicAdd(&norm_s[mf * 16 + hi * 4 + r], v);
    }
  __syncthreads();
  if (t < MROWS) norms[row0 + t] = norm_s[t];
}

// ---- fused distance MFMA (256c x 256q, 1024 threads / 16 waves) ----
// counted-vmcnt dbuf; 4 waves/SIMD in one resident block; wave = 64c x 64q.
// grid: 640 flat, XCD-swizzled: xcd=flat%8 owns chunk xcd (20 ct2 x 4 qt).
__global__ __launch_bounds__(1024, 4)
void k_dist(const u16* __restrict__ h_bf, const float* __restrict__ norms,
            const int* __restrict__ cand_y,
            float* __restrict__ cls_part, float* __restrict__ lse_part)
{
  // dbuf: [buf][A 256x64 | B 256x64] bf16; 2 x 64 KB = 128 KB.
  // Epilogue reuses the front as P_s[256][136] (69.6 KB).
  __shared__ __align__(16) u16 AB_s[65536];
  __shared__ float qn_s[256];
  __shared__ float cn_s[256];
  __shared__ int cy_s[256];
  __shared__ float lse_s[256];

  u16* P_s = AB_s;

  const int flat = blockIdx.x;
  const int xcd = flat & 7;
  const int i = flat >> 3;                 // 0..79
  const int ctl = i >> 2;                  // 0..19
  const int qt = i & 3;                    // 0..3
  const int chunk = xcd;
  const int ct2 = chunk * CT2_PER_CHUNK + ctl;

  const int t = threadIdx.x;
  const int cand0 = chunk * CHUNKSZ + ctl * 256;
  const int cend = chunk * CHUNKSZ + CHUNKSZ;
  const int q0 = qt * 256;

  if (t < 256) {
    lse_s[t] = 0.f;
    qn_s[t] = norms[q0 + t];
    int j = cand0 + t; if (j > cend - 1) j = cend - 1;
    cn_s[t] = norms[BQ + j];
    cy_s[t] = cand_y[j];
  }

  const int wid = t >> 6, l = t & 63, hi = l >> 4, lo = l & 15;
  const int wc = wid & 3, wq = wid >> 2;   // wave: cand quarter (64) x q quarter (64)

  // stage one K-step: A(256x64) -> AB_s[dstoff], B(256x64) -> +16384 (u16 units).
  // 1024 threads -> 2 segs/thread per operand (4 loads/thread total).
  // LDS dest LINEAR; source col pre-swizzled (inverse of read swizzle).
#define STAGE(dstoff, kt)                                                      \
  {                                                                            \
    _Pragma("unroll")                                                          \
    for (int p = 0; p < 2; ++p) {                                              \
      int s = p * 1024 + t;                                                    \
      int lrow = s >> 3;                                                       \
      int scol = ((s & 7) * 16) ^ ((lrow & 7) << 4);                           \
      int crow = cand0 + lrow; if (crow > cend - 1) crow = cend - 1;           \
      const u16* srcA = h_bf + (size_t)(BQ + crow) * DIM + (kt) * 64 + (scol >> 1); \
      __builtin_amdgcn_global_load_lds(                                        \
          (const __attribute__((address_space(1))) u32*)srcA,                  \
          (__attribute__((address_space(3))) u32*)(AB_s + (dstoff) + s * 8),   \
          16, 0, 0);                                                           \
      const u16* srcB = h_bf + (size_t)(q0 + lrow) * DIM + (kt) * 64 + (scol >> 1); \
      __builtin_amdgcn_global_load_lds(                                        \
          (const __attribute__((address_space(1))) u32*)srcB,                  \
          (__attribute__((address_space(3))) u32*)(AB_s + (dstoff) + 16384 + s * 8), \
          16, 0, 0);                                                           \
    }                                                                          \
  }

  f32x4 acc[4][4];
#pragma unroll
  for (int mi = 0; mi < 4; ++mi)
#pragma unroll
    for (int ni = 0; ni < 4; ++ni) acc[mi][ni] = 0.f;

  STAGE(0, 0);          // 4 loads/thread in flight
  STAGE(32768, 1);      // 8 in flight

#pragma unroll
  for (int kt = 0; kt < 8; ++kt) {
    // wait ONLY for stage(kt): stage(kt+1)'s 4 may stay outstanding
    if (kt == 7) asm volatile("s_waitcnt vmcnt(0)" ::: "memory");
    else         asm volatile("s_waitcnt vmcnt(4)" ::: "memory");
    __builtin_amdgcn_s_barrier();            // all waves' stage(kt) landed
    __builtin_amdgcn_sched_barrier(0);

    const u16* Ac = AB_s + (kt & 1) * 32768;
    const u16* Bc = Ac + 16384;
    __builtin_amdgcn_s_setprio(1);
#pragma unroll
    for (int ks = 0; ks < 2; ++ks) {
      bf16x8 af[4], bq[4];
#pragma unroll
      for (int mi = 0; mi < 4; ++mi) {
        int row = wc * 64 + mi * 16 + lo;
        int byt = (hi * 16 + ks * 64) ^ ((row & 7) << 4);
        af[mi] = *(const bf16x8*)&Ac[row * 64 + (byt >> 1)];
      }
#pragma unroll
      for (int ni = 0; ni < 4; ++ni) {
        int row = wq * 64 + ni * 16 + lo;
        int byt = (hi * 16 + ks * 64) ^ ((row & 7) << 4);
        bq[ni] = *(const bf16x8*)&Bc[row * 64 + (byt >> 1)];
      }
#pragma unroll
      for (int mi = 0; mi < 4; ++mi)
#pragma unroll
        for (int ni = 0; ni < 4; ++ni)
          acc[mi][ni] = __builtin_amdgcn_mfma_f32_16x16x32_bf16(af[mi], bq[ni], acc[mi][ni], 0, 0, 0);
    }
    __builtin_amdgcn_s_setprio(0);
    __builtin_amdgcn_sched_barrier(0);
    __builtin_amdgcn_s_barrier();            // all waves done READING buf[kt&1]
    if (kt < 6) STAGE((kt & 1) * 32768, kt + 2);   // refill freed buffer
  }
#undef STAGE

  // epilogue: d2 -> dist -> e (packed to bf16 in regs) + lse partial
  float qv[4];
#pragma unroll
  for (int ni = 0; ni < 4; ++ni) qv[ni] = qn_s[wq * 64 + ni * 16 + lo];

  u32 pk[4][4][2];
  float lacc[4] = {0.f, 0.f, 0.f, 0.f};
#pragma unroll
  for (int mi = 0; mi < 4; ++mi)
#pragma unroll
    for (int ni = 0; ni < 4; ++ni) {
      float ev[4];
#pragma unroll
      for (int r = 0; r < 4; ++r) {
        int crow = wc * 64 + mi * 16 + hi * 4 + r;
        bool valid = (cand0 + crow) < cend;
        float d2 = fmaf(-2.f, acc[mi][ni][r], cn_s[crow] + qv[ni]);
        float dist = __builtin_amdgcn_sqrtf(fmaxf(d2, 1e-12f));
        float e = valid ? __expf(-dist) : 0.f;
        ev[r] = e;
        lacc[ni] += valid ? __expf(e) : 0.f;
      }
      pk[mi][ni][0] = cvt_pk_bf16(ev[0], ev[1]);
      pk[mi][ni][1] = cvt_pk_bf16(ev[2], ev[3]);
    }

  // LSE partial: reduce across the 4 hi-groups (j spread over hi)
#pragma unroll
  for (int ni = 0; ni < 4; ++ni) {
    float v = lacc[ni];
    v += __shfl_xor(v, 16); v += __shfl_xor(v, 32);
    if (hi == 0) atomicAdd(&lse_s[wq * 64 + ni * 16 + lo], v);
  }

  // class-sum GEMM in two cand-halves of 128: P_s[256 q][128 j + pad].
  f32x4 accc = {0.f, 0.f, 0.f, 0.f};
#pragma unroll
  for (int h = 0; h < 2; ++h) {
    __syncthreads();   // previous AB_s/P_s readers done
    if ((wc >> 1) == h) {
#pragma unroll
      for (int mi = 0; mi < 4; ++mi)
#pragma unroll
        for (int ni = 0; ni < 4; ++ni) {
          int q = wq * 64 + ni * 16 + lo;
          int j0 = (wc & 1) * 64 + mi * 16 + hi * 4;
          *(uint2*)&P_s[q * PSTRIDE + j0] = make_uint2(pk[mi][ni][0], pk[mi][ni][1]);
        }
    }
    __syncthreads();
    // each wave owns q-group wid*16..+15: out[q][c] += P[q][j 0..127] @ onehot
    const u16* Prow = P_s + (wid * 16 + lo) * PSTRIDE;
#pragma unroll
    for (int ks = 0; ks < 4; ++ks) {
      bf16x8 af = *(const bf16x8*)(Prow + ks * 32 + hi * 8);
      bf16x8 yb;
#pragma unroll
      for (int e = 0; e < 8; ++e) {
        int j = h * 128 + ks * 32 + hi * 8 + e;
        yb[e] = (short)((cy_s[j] == lo) ? 0x3F80 : 0);
      }
      accc = __builtin_amdgcn_mfma_f32_16x16x32_bf16(af, yb, accc, 0, 0, 0);
    }
  }
  if (lo < NCLS) {
#pragma unroll
    for (int reg = 0; reg < 4; ++reg) {
      int qq = wid * 16 + hi * 4 + reg;
      cls_part[((size_t)ct2 * BQ + (q0 + qq)) * NCLS + lo] = accc[reg];
    }
  }

  if (t < 256) lse_part[(size_t)ct2 * BQ + q0 + t] = lse_s[t];
}

// ---- combine partials over 160 cand tiles ----
__global__ __launch_bounds__(256)
void k_final(const float* __restrict__ cls_part, const float* __restrict__ lse_part,
             float* __restrict__ out)
{
  __shared__ float cls_sum[NCLS];
  __shared__ float ch_sum[NCHUNK];
  const int t = threadIdx.x;   // 0..255; tiles at t<160
  const int b = blockIdx.x;
  if (t < NCLS) cls_sum[t] = 0.f;
  if (t < NCHUNK) ch_sum[t] = 0.f;
  __syncthreads();

  float cs[NCLS];
  float ls = 0.f;
  if (t < NCT2) {
#pragma unroll
    for (int c = 0; c < NCLS; ++c) cs[c] = cls_part[((size_t)t * BQ + b) * NCLS + c];
    ls = lse_part[(size_t)t * BQ + b];
    atomicAdd(&ch_sum[t / CT2_PER_CHUNK], ls);
  } else {
#pragma unroll
    for (int c = 0; c < NCLS; ++c) cs[c] = 0.f;
  }
#pragma unroll
  for (int c = 0; c < NCLS; ++c) {
    float w = cs[c];
    w += __shfl_xor(w, 1); w += __shfl_xor(w, 2); w += __shfl_xor(w, 4);
    w += __shfl_xor(w, 8); w += __shfl_xor(w, 16); w += __shfl_xor(w, 32);
    if ((t & 63) == 0) atomicAdd(&cls_sum[c], w);
  }
  __syncthreads();
  if (t < NCLS) {
    float lse = 0.f;
#pragma unroll
    for (int ch = 0; ch < NCHUNK; ++ch) lse += logf(ch_sum[ch]);
    out[b * NCLS + t] = logf(cls_sum[t]) - lse;
  }
}

extern "C" void kernel_launch(void* const* d_in, const int* in_sizes, int n_in,
                              void* d_out, int out_size, void* d_ws, size_t ws_size,
                              hipStream_t stream)
{
  const float* xq_num = (const float*)d_in[0];
  const float* xq_cat = (const float*)d_in[1];
  // d_in[2] = y (unused)
  const float* xc_num = (const float*)d_in[3];
  const float* xc_cat = (const float*)d_in[4];
  const int* cand_y = (const int*)d_in[5];
  const float* freq = (const float*)d_in[6];
  const float* lin_w = (const float*)d_in[7];
  const float* lin_b = (const float*)d_in[8];
  const float* enc_w = (const float*)d_in[9];
  const float* enc_b = (const float*)d_in[10];

  u16* h_bf = (u16*)d_ws;                                        // 41024*512 bf16
  float* norms = (float*)((char*)d_ws + (size_t)ROWS_TOT * DIM * 2);
  float* cls_part = norms + ROWS_TOT;                            // [160][1024][10]
  float* lse_part = cls_part + (size_t)NCT2 * BQ * NCLS;         // [160][1024]
  u16* enc_wT = (u16*)(lse_part + (size_t)NCT2 * BQ);            // [512][800]
  float* out = (float*)d_out;

  hipLaunchKernelGGL(k_prep, dim3(13 * 8), dim3(256), 0, stream, enc_w, enc_wT);
  hipLaunchKernelGGL(k_encode, dim3(ROWS_TOT / MROWS), dim3(1024), 0, stream,
                     xq_num, xq_cat, xc_num, xc_cat, freq, lin_w, lin_b,
                     enc_wT, enc_b, h_bf, norms);
  hipLaunchKernelGGL(k_dist, dim3(NCT2 * 4), dim3(1024), 0, stream,
                     h_bf, norms, cand_y, cls_part, lse_part);
  hipLaunchKernelGGL(k_final, dim3(BQ), dim3(256), 0, stream,
                     cls_part, lse_part, out);
}